// Round 13
// baseline (43.361 us; speedup 1.0000x reference)
//
#include <hip/hip_runtime.h>
#include <math.h>

#define WIDTH 8192
#define NROW  2048                    // B*C = 16*128
#define T4    2048                    // float4 slots per row
#define NSLOT (NROW * T4)             // 4,194,304 flat slots
#define HALF  (NSLOT / 2)             // 2,097,152 (multiple of T4 -> row-safe)
#define NBLK  1024
#define NTHR  256
#define SSTEP (NBLK * NTHR)           // 262,144 slots per sweep (per half)
#define ITERS (HALF / SSTEP)          // 8 iterations per thread

// compare-exchange: a=min, b=max
#define CE(a, b) { float _lo = fminf(a, b); float _hi = fmaxf(a, b); (a) = _lo; (b) = _hi; }

// One window, fully independent (ILP across 8 windows/iter):
//   sort4{e1..e4} + sort3{e5..e7} + merge-rank-select (r6-verified formula).
#define WINDOW(I, DST) {                                                      \
    const unsigned wb = (bits >> ((I) + 1)) & 0x7Fu;                          \
    const int n = __popc(wb);                                                 \
    float a0 = (wb & 1u)  ? xv[(I) + 1] : INF;                                \
    float a1 = (wb & 2u)  ? xv[(I) + 2] : INF;                                \
    float a2 = (wb & 4u)  ? xv[(I) + 3] : INF;                                \
    float a3 = (wb & 8u)  ? xv[(I) + 4] : INF;                                \
    float t0 = (wb & 16u) ? xv[(I) + 5] : INF;                                \
    float t1 = (wb & 32u) ? xv[(I) + 6] : INF;                                \
    float t2 = (wb & 64u) ? xv[(I) + 7] : INF;                                \
    CE(a0, a1); CE(a2, a3); CE(a0, a2); CE(a1, a3); CE(a1, a2);  /* sort4 */  \
    CE(t0, t1); CE(t1, t2); CE(t0, t1);                          /* sort3 */  \
    const float M0 = fminf(a0, t0);                                           \
    const float M1 = fminf(fminf(a1, t1), fmaxf(a0, t0));                     \
    const float M2 = fminf(fminf(a2, t2),                                     \
                           fminf(fmaxf(a1, t0), fmaxf(a0, t1)));              \
    const float M3 = fminf(fminf(a3, fmaxf(a2, t0)),                          \
                           fminf(fmaxf(a1, t1), fmaxf(a0, t2)));              \
    const int k = (n - 1) >> 1;                                               \
    float med = (k <= 0) ? M0 : (k == 1) ? M1 : (k == 2) ? M2 : M3;           \
    (DST) = (n == 0) ? __builtin_nanf("") : med; }

// Branchless tile load: edge threads re-load their own slot; validity nibble
// is zeroed via EM instead. All 6 loads unconditional -> clause together.
#define LOAD_TILE(S, X0, X1, X2, M0, M1, M2, EM) {                            \
    const int _t  = (S) & (T4 - 1);                                           \
    const int _sm = (S) - ((_t > 0)      ? 1 : 0);                            \
    const int _sp = (S) + ((_t < T4 - 1) ? 1 : 0);                            \
    X0 = x4[_sm];  X1 = x4[(S)];  X2 = x4[_sp];                               \
    M0 = m4[_sm];  M1 = m4[(S)];  M2 = m4[_sp];                               \
    EM = ((_t > 0) ? 0xFu : 0u) | 0xF0u | ((_t < T4 - 1) ? 0xF00u : 0u); }

__device__ __forceinline__ float4 compute_tile(float4 X0, float4 X1, float4 X2,
                                               int4 M0, int4 M1, int4 M2,
                                               unsigned em) {
    const float INF = __builtin_inff();
    // compare-free packing: jax-bool -> int32 marshalling is exactly 0/1
    const unsigned bits =
        (((unsigned)M0.x)       | ((unsigned)M0.y << 1) |
         ((unsigned)M0.z << 2)  | ((unsigned)M0.w << 3) |
         ((unsigned)M1.x << 4)  | ((unsigned)M1.y << 5) |
         ((unsigned)M1.z << 6)  | ((unsigned)M1.w << 7) |
         ((unsigned)M2.x << 8)  | ((unsigned)M2.y << 9) |
         ((unsigned)M2.z << 10) | ((unsigned)M2.w << 11)) & em;
    const float xv[12] = { X0.x, X0.y, X0.z, X0.w,
                           X1.x, X1.y, X1.z, X1.w,
                           X2.x, X2.y, X2.z, X2.w };
    float o_0, o_1, o_2, o_3;
    WINDOW(0, o_0);
    WINDOW(1, o_1);
    WINDOW(2, o_2);
    WINDOW(3, o_3);
    return make_float4(o_0, o_1, o_2, o_3);
}

__launch_bounds__(NTHR)
__global__ void mmp_kernel(const float* __restrict__ x,
                           const int* __restrict__ mask,
                           float* __restrict__ out) {
    const float4* x4 = (const float4*)x;
    const int4*   m4 = (const int4*)mask;
    float4*       o4 = (float4*)out;

    const int sid0 = blockIdx.x * NTHR + threadIdx.x;   // first flat slot

    // ---- two current tiles (A: lower half, P: upper half) ----
    float4 XA0, XA1, XA2, XP0, XP1, XP2;
    int4   MA0, MA1, MA2, MP0, MP1, MP2;
    unsigned emA, emP;
    LOAD_TILE(sid0,        XA0, XA1, XA2, MA0, MA1, MA2, emA);
    LOAD_TILE(sid0 + HALF, XP0, XP1, XP2, MP0, MP1, MP2, emP);

#pragma unroll
    for (int it = 0; it < ITERS; ++it) {
        const int s = sid0 + it * SSTEP;

        // ---- prefetch next pair BEFORE computing current pair ----
        float4 XB0, XB1, XB2, XQ0, XQ1, XQ2;
        int4   MB0, MB1, MB2, MQ0, MQ1, MQ2;
        unsigned emB = 0, emQ = 0;
        if (it < ITERS - 1) {                        // compile-time after unroll
            LOAD_TILE(s + SSTEP,        XB0, XB1, XB2, MB0, MB1, MB2, emB);
            LOAD_TILE(s + SSTEP + HALF, XQ0, XQ1, XQ2, MQ0, MQ1, MQ2, emQ);
        } else {
            XB0 = XA0; XB1 = XA1; XB2 = XA2; MB0 = MA0; MB1 = MA1; MB2 = MA2;
            XQ0 = XP0; XQ1 = XP1; XQ2 = XP2; MQ0 = MP0; MQ1 = MP1; MQ2 = MP2;
        }

        // ---- compute both tiles (8 independent windows of ILP) ----
        o4[s]        = compute_tile(XA0, XA1, XA2, MA0, MA1, MA2, emA);
        o4[s + HALF] = compute_tile(XP0, XP1, XP2, MP0, MP1, MP2, emP);

        // ---- rotate (static, fully unrolled — registers only) ----
        XA0 = XB0; XA1 = XB1; XA2 = XB2; MA0 = MB0; MA1 = MB1; MA2 = MB2;
        XP0 = XQ0; XP1 = XQ1; XP2 = XQ2; MP0 = MQ0; MP1 = MQ1; MP2 = MQ2;
        emA = emB; emP = emQ;
    }
}

extern "C" void kernel_launch(void* const* d_in, const int* in_sizes, int n_in,
                              void* d_out, int out_size, void* d_ws, size_t ws_size,
                              hipStream_t stream) {
    const float* x    = (const float*)d_in[0];
    const int*   mask = (const int*)d_in[1];
    float*       outp = (float*)d_out;

    mmp_kernel<<<NBLK, NTHR, 0, stream>>>(x, mask, outp);
}

// Round 14
// 39.693 us; speedup vs baseline: 1.0924x; 1.0924x over previous
//
#include <hip/hip_runtime.h>
#include <math.h>

#define WIDTH 8192
#define NROW  2048                    // B*C = 16*128
#define T4    2048                    // float4 slots per row
#define NSLOT (NROW * T4)             // 4,194,304 flat slots
#define NBLK  2048
#define NTHR  256
#define SSTEP (NBLK * NTHR)           // 524,288 slots per sweep
#define ITERS (NSLOT / SSTEP)         // 8 iterations per thread

// compare-exchange: a=min, b=max
#define CE(a, b) { float _lo = fminf(a, b); float _hi = fmaxf(a, b); (a) = _lo; (b) = _hi; }

// One window, fully independent (ILP×4 across windows):
//   sort4{e1..e4} + sort3{e5..e7} + merge-rank-select (r6-verified formula).
#define WINDOW(I, DST) {                                                      \
    const unsigned wb = (bits >> ((I) + 1)) & 0x7Fu;                          \
    const int n = __popc(wb);                                                 \
    float a0 = (wb & 1u)  ? xv[(I) + 1] : INF;                                \
    float a1 = (wb & 2u)  ? xv[(I) + 2] : INF;                                \
    float a2 = (wb & 4u)  ? xv[(I) + 3] : INF;                                \
    float a3 = (wb & 8u)  ? xv[(I) + 4] : INF;                                \
    float t0 = (wb & 16u) ? xv[(I) + 5] : INF;                                \
    float t1 = (wb & 32u) ? xv[(I) + 6] : INF;                                \
    float t2 = (wb & 64u) ? xv[(I) + 7] : INF;                                \
    CE(a0, a1); CE(a2, a3); CE(a0, a2); CE(a1, a3); CE(a1, a2);  /* sort4 */  \
    CE(t0, t1); CE(t1, t2); CE(t0, t1);                          /* sort3 */  \
    const float M0 = fminf(a0, t0);                                           \
    const float M1 = fminf(fminf(a1, t1), fmaxf(a0, t0));                     \
    const float M2 = fminf(fminf(a2, t2),                                     \
                           fminf(fmaxf(a1, t0), fmaxf(a0, t1)));              \
    const float M3 = fminf(fminf(a3, fmaxf(a2, t0)),                          \
                           fminf(fmaxf(a1, t1), fmaxf(a0, t2)));              \
    const int k = (n - 1) >> 1;                                               \
    float med = (k <= 0) ? M0 : (k == 1) ? M1 : (k == 2) ? M2 : M3;           \
    (DST) = (n == 0) ? __builtin_nanf("") : med; }

// Branchless tile load: edge threads re-load their own slot; validity nibble
// is zeroed via EM instead. All 6 loads unconditional -> clause together.
#define LOAD_TILE(S, X0, X1, X2, M0, M1, M2, EM) {                            \
    const int _t  = (S) & (T4 - 1);                                           \
    const int _sm = (S) - ((_t > 0)      ? 1 : 0);                            \
    const int _sp = (S) + ((_t < T4 - 1) ? 1 : 0);                            \
    X0 = x4[_sm];  X1 = x4[(S)];  X2 = x4[_sp];                               \
    M0 = m4[_sm];  M1 = m4[(S)];  M2 = m4[_sp];                               \
    EM = ((_t > 0) ? 0xFu : 0u) | 0xF0u | ((_t < T4 - 1) ? 0xF00u : 0u); }

__launch_bounds__(NTHR)
__global__ void mmp_kernel(const float* __restrict__ x,
                           const int* __restrict__ mask,
                           float* __restrict__ out) {
    const float4* x4 = (const float4*)x;
    const int4*   m4 = (const int4*)mask;
    float4*       o4 = (float4*)out;

    const int   sid0 = blockIdx.x * NTHR + threadIdx.x;   // first flat slot
    const float INF  = __builtin_inff();

    // ---- tile A (current) — prologue load ----
    float4 XA0, XA1, XA2; int4 MA0, MA1, MA2; unsigned emA;
    LOAD_TILE(sid0, XA0, XA1, XA2, MA0, MA1, MA2, emA);

#pragma unroll
    for (int it = 0; it < ITERS; ++it) {
        const int s = sid0 + it * SSTEP;

        // ---- issue next tile's 6 loads ----
        float4 XB0, XB1, XB2; int4 MB0, MB1, MB2; unsigned emB = 0;
        if (it < ITERS - 1) {                        // compile-time after unroll
            LOAD_TILE(s + SSTEP, XB0, XB1, XB2, MB0, MB1, MB2, emB);
        } else {
            XB0 = XA0; XB1 = XA1; XB2 = XA2;         // dead values, keep defined
            MB0 = MA0; MB1 = MA1; MB2 = MA2;
        }

        // ---- FENCE: forbid the compiler from sinking the B-loads below the
        //      compute (VGPR=36 across r10-r13 proved it was doing exactly
        //      that — the "prefetch" never existed). After this barrier the
        //      B-loads are in flight during ~400 cycles of sort work. ----
        __builtin_amdgcn_sched_barrier(0);

        // ---- compute tile A: compare-free packing (mask ints are 0/1) ----
        const unsigned bits =
            (((unsigned)MA0.x)       | ((unsigned)MA0.y << 1) |
             ((unsigned)MA0.z << 2)  | ((unsigned)MA0.w << 3) |
             ((unsigned)MA1.x << 4)  | ((unsigned)MA1.y << 5) |
             ((unsigned)MA1.z << 6)  | ((unsigned)MA1.w << 7) |
             ((unsigned)MA2.x << 8)  | ((unsigned)MA2.y << 9) |
             ((unsigned)MA2.z << 10) | ((unsigned)MA2.w << 11)) & emA;
        const float xv[12] = { XA0.x, XA0.y, XA0.z, XA0.w,
                               XA1.x, XA1.y, XA1.z, XA1.w,
                               XA2.x, XA2.y, XA2.z, XA2.w };

        float o_0, o_1, o_2, o_3;
        WINDOW(0, o_0);
        WINDOW(1, o_1);
        WINDOW(2, o_2);
        WINDOW(3, o_3);
        o4[s] = make_float4(o_0, o_1, o_2, o_3);

        // ---- rotate B -> A (static, fully unrolled — registers only) ----
        XA0 = XB0; XA1 = XB1; XA2 = XB2;
        MA0 = MB0; MA1 = MB1; MA2 = MB2;
        emA = emB;
    }
}

extern "C" void kernel_launch(void* const* d_in, const int* in_sizes, int n_in,
                              void* d_out, int out_size, void* d_ws, size_t ws_size,
                              hipStream_t stream) {
    const float* x    = (const float*)d_in[0];
    const int*   mask = (const int*)d_in[1];
    float*       outp = (float*)d_out;

    mmp_kernel<<<NBLK, NTHR, 0, stream>>>(x, mask, outp);
}